// Round 3
// baseline (13098.445 us; speedup 1.0000x reference)
//
#include <hip/hip_runtime.h>
#include <hip/hip_bf16.h>
#include <float.h>
#include <math.h>

// Transformer forward. Round 3: big GEMMs moved to bf16 MFMA (fp32 in HBM,
// convert-to-bf16 during LDS staging, fp32 accumulate). Attention path stays
// fp32 vector this round (scoped experiment: learn bf16 tolerance).
// B=2, N=1024, D=1024, H=16, DH=64, L=6, INNER=2730.
// ws layout (floats): X(2M) | H(2M) | Q(2M) | KV(4M) | O(2M) | P2(2M) | PR(16.84M)
// PR reused: attn probs [16][1024][1028], or FF U[2048][5460]+GG[2048][2732].
// Total ws requirement: 31,522,816 floats = 126,091,264 bytes (unchanged).

#define N_SEQ 1024
#define DMODEL 1024
#define NH 16
#define DH 64
#define NLAYER 6
#define FF_INNER 2730
#define GG_LD 2732     // padded row stride for GG (16B-aligned rows)
#define PSTRIDE 1028   // padded row stride for probs rows of length 1025

typedef float f32x4 __attribute__((ext_vector_type(4)));
typedef short s16x8 __attribute__((ext_vector_type(8)));
typedef unsigned long long u64;

__device__ __forceinline__ ushort f2bf(float f) {
  return __builtin_bit_cast(ushort, __float2bfloat16(f));
}
__device__ __forceinline__ u64 pack4(float a, float b, float c, float d) {
  return (u64)f2bf(a) | ((u64)f2bf(b) << 16) | ((u64)f2bf(c) << 32) |
         ((u64)f2bf(d) << 48);
}

// ---------------- block reductions (256 threads = 4 waves) ----------------
__device__ __forceinline__ float wave_sum(float v) {
#pragma unroll
  for (int o = 32; o > 0; o >>= 1) v += __shfl_xor(v, o, 64);
  return v;
}
__device__ __forceinline__ float wave_max(float v) {
#pragma unroll
  for (int o = 32; o > 0; o >>= 1) v = fmaxf(v, __shfl_xor(v, o, 64));
  return v;
}
__device__ __forceinline__ float block_sum(float v, float* s) {
  v = wave_sum(v);
  __syncthreads();
  if ((threadIdx.x & 63) == 0) s[threadIdx.x >> 6] = v;
  __syncthreads();
  return s[0] + s[1] + s[2] + s[3];
}
__device__ __forceinline__ float block_max(float v, float* s) {
  v = wave_max(v);
  __syncthreads();
  if ((threadIdx.x & 63) == 0) s[threadIdx.x >> 6] = v;
  __syncthreads();
  return fmaxf(fmaxf(s[0], s[1]), fmaxf(s[2], s[3]));
}

// ---------------- LayerNorm (optionally residual-add into out) ----------------
template <int RES>
__global__ __launch_bounds__(256) void ln_kernel(const float* __restrict__ in,
                                                 const float* __restrict__ gw,
                                                 const float* __restrict__ bw,
                                                 float* __restrict__ out) {
  __shared__ float red[4];
  const int row = blockIdx.x, t = threadIdx.x;
  float4 v = *(const float4*)(in + (size_t)row * DMODEL + t * 4);
  float mean = block_sum(v.x + v.y + v.z + v.w, red) * (1.0f / DMODEL);
  float4 d = make_float4(v.x - mean, v.y - mean, v.z - mean, v.w - mean);
  float var = block_sum(d.x * d.x + d.y * d.y + d.z * d.z + d.w * d.w, red) * (1.0f / DMODEL);
  float rstd = rsqrtf(var + 1e-5f);
  float4 g4 = *(const float4*)(gw + t * 4);
  float4 b4 = *(const float4*)(bw + t * 4);
  float4 r = make_float4(d.x * rstd * g4.x + b4.x, d.y * rstd * g4.y + b4.y,
                         d.z * rstd * g4.z + b4.z, d.w * rstd * g4.w + b4.w);
  float* q = out + (size_t)row * DMODEL + t * 4;
  if (RES) {
    float4 xv = *(float4*)q;
    r.x += xv.x; r.y += xv.y; r.z += xv.z; r.w += xv.w;
  }
  *(float4*)q = r;
}

// ---------------- final: x / rowmax(x), then LN ----------------
__global__ __launch_bounds__(256) void final_kernel(const float* __restrict__ in,
                                                    const float* __restrict__ gw,
                                                    const float* __restrict__ bw,
                                                    float* __restrict__ out) {
  __shared__ float red[4];
  const int row = blockIdx.x, t = threadIdx.x;
  float4 v = *(const float4*)(in + (size_t)row * DMODEL + t * 4);
  float mx = block_max(fmaxf(fmaxf(v.x, v.y), fmaxf(v.z, v.w)), red);
  float4 y = make_float4(v.x / mx, v.y / mx, v.z / mx, v.w / mx);
  float mean = block_sum(y.x + y.y + y.z + y.w, red) * (1.0f / DMODEL);
  float4 d = make_float4(y.x - mean, y.y - mean, y.z - mean, y.w - mean);
  float var = block_sum(d.x * d.x + d.y * d.y + d.z * d.z + d.w * d.w, red) * (1.0f / DMODEL);
  float rstd = rsqrtf(var + 1e-5f);
  float4 g4 = *(const float4*)(gw + t * 4);
  float4 b4 = *(const float4*)(bw + t * 4);
  float4 r = make_float4(d.x * rstd * g4.x + b4.x, d.y * rstd * g4.y + b4.y,
                         d.z * rstd * g4.z + b4.z, d.w * rstd * g4.w + b4.w);
  *(float4*)(out + (size_t)row * DMODEL + t * 4) = r;
}

// ---------------- bf16-MFMA GEMM: C[2048,N] = A[2048,K](lda) @ W[K,N] (+bias) ----------------
// 128x128 tile, BK=32, 256 threads = 4 waves (2x2), each wave 64x64 via
// 4x4 grid of mfma_f32_16x16x32_bf16. A,B staged K-innermost in LDS
// ([row][k], 36-el padded rows -> 8B-aligned ds_read_b64 fragments,
// stride 18 words => 16-distinct-bank reads).
// A frag: lane l holds row (l&15), k=(l>>4)*8+j. B frag: col (l&15), same k.
// C/D: col=lane&15, row=(lane>>4)*4+reg (verified layout, learn_hip m89/m91).
__global__ __launch_bounds__(256) void gemm_mfma(const float* __restrict__ A,
                                                 const float* __restrict__ W,
                                                 const float* __restrict__ bias,
                                                 float* __restrict__ C,
                                                 int N, int K, int lda) {
  __shared__ ushort Alds[128 * 36];
  __shared__ ushort Blds[128 * 36];
  const int n0 = blockIdx.x * 128, m0 = blockIdx.y * 128;
  const int t = threadIdx.x;
  const int lane = t & 63, warp = t >> 6;
  const int wm = warp >> 1, wn = warp & 1;

  f32x4 acc[4][4];
#pragma unroll
  for (int i = 0; i < 4; i++)
#pragma unroll
    for (int j = 0; j < 4; j++) acc[i][j] = (f32x4){0.f, 0.f, 0.f, 0.f};

  const int sa_m = t >> 2;            // 0..63
  const int sa_kg = t & 3;            // 0..3 (float4 group)
  const int sb_n = t & 127;           // 0..127
  const int sb_kb = (t >> 7) * 16;    // 0 or 16

  for (int k0 = 0; k0 < K; k0 += 32) {
    // ---- stage A: 128m x 32k fp32 -> bf16 LDS [m][k] ----
#pragma unroll
    for (int h = 0; h < 4; h++) {
      int m = sa_m + (h >> 1) * 64;
      int kg = sa_kg + (h & 1) * 4;
      int gk = k0 + kg * 4;
      const float* src = A + (size_t)(m0 + m) * lda + gk;
      float x0, x1, x2, x3;
      if (gk + 3 < K) {
        float4 v = *(const float4*)src;
        x0 = v.x; x1 = v.y; x2 = v.z; x3 = v.w;
      } else {
        x0 = (gk + 0 < K) ? src[0] : 0.f;
        x1 = (gk + 1 < K) ? src[1] : 0.f;
        x2 = (gk + 2 < K) ? src[2] : 0.f;
        x3 = (gk + 3 < K) ? src[3] : 0.f;
      }
      *(u64*)&Alds[m * 36 + kg * 4] = pack4(x0, x1, x2, x3);
    }
    // ---- stage B: 32k x 128n fp32 -> bf16 LDS transposed [n][k] ----
    {
      int gn = n0 + sb_n;
      bool nok = gn < N;
      float v[16];
#pragma unroll
      for (int i = 0; i < 16; i++) {
        int gk = k0 + sb_kb + i;
        v[i] = (nok && gk < K) ? W[(size_t)gk * N + gn] : 0.f;
      }
      u64* dst = (u64*)&Blds[sb_n * 36 + sb_kb];
      dst[0] = pack4(v[0], v[1], v[2], v[3]);
      dst[1] = pack4(v[4], v[5], v[6], v[7]);
      dst[2] = pack4(v[8], v[9], v[10], v[11]);
      dst[3] = pack4(v[12], v[13], v[14], v[15]);
    }
    __syncthreads();

    union FR { u64 q[2]; s16x8 s; };
    FR fa[4], fb[4];
    const int kk = (lane >> 4) * 8;
    const int ar = wm * 64 + (lane & 15);
    const int br = wn * 64 + (lane & 15);
#pragma unroll
    for (int mi = 0; mi < 4; mi++) {
      const ushort* p = &Alds[(ar + mi * 16) * 36 + kk];
      fa[mi].q[0] = *(const u64*)p;
      fa[mi].q[1] = *(const u64*)(p + 4);
    }
#pragma unroll
    for (int ni = 0; ni < 4; ni++) {
      const ushort* p = &Blds[(br + ni * 16) * 36 + kk];
      fb[ni].q[0] = *(const u64*)p;
      fb[ni].q[1] = *(const u64*)(p + 4);
    }
#pragma unroll
    for (int mi = 0; mi < 4; mi++)
#pragma unroll
      for (int ni = 0; ni < 4; ni++)
        acc[mi][ni] = __builtin_amdgcn_mfma_f32_16x16x32_bf16(
            fa[mi].s, fb[ni].s, acc[mi][ni], 0, 0, 0);
    __syncthreads();
  }

  // ---- epilogue ----
  const int crow = m0 + wm * 64 + (lane >> 4) * 4;
  const int ccol = n0 + wn * 64 + (lane & 15);
#pragma unroll
  for (int ni = 0; ni < 4; ni++) {
    int gc = ccol + ni * 16;
    if (gc >= N) continue;
    float bv = bias ? bias[gc] : 0.f;
#pragma unroll
    for (int mi = 0; mi < 4; mi++) {
#pragma unroll
      for (int r = 0; r < 4; r++)
        C[(size_t)(crow + mi * 16 + r) * N + gc] = acc[mi][ni][r] + bv;
    }
  }
}

// ---------------- attention scores: sim[h,i,j] = SCALE * q[i]·k[j], causal mask ----------------
__global__ __launch_bounds__(256) void scores_kernel(const float* __restrict__ q,
                                                     const float* __restrict__ kv,
                                                     const float* __restrict__ nullk,
                                                     float* __restrict__ probs, int b) {
  __shared__ float Qs[64][68];  // [d][i]
  __shared__ float Ks[64][68];  // [d][j]
  const int h = blockIdx.z, i0 = blockIdx.y * 64, j0 = blockIdx.x * 64;
  const int t = threadIdx.x, tx = t & 15, ty = t >> 4;
#pragma unroll
  for (int r = 0; r < 4; r++) {
    int f = t + r * 256;
    int i = f >> 4, d4 = (f & 15) << 2;
    float4 v = *(const float4*)(q + ((size_t)(b * N_SEQ) + i0 + i) * DMODEL + h * DH + d4);
    Qs[d4 + 0][i] = v.x; Qs[d4 + 1][i] = v.y; Qs[d4 + 2][i] = v.z; Qs[d4 + 3][i] = v.w;
  }
#pragma unroll
  for (int r = 0; r < 4; r++) {
    int f = t + r * 256;
    int j = f >> 4, d4 = (f & 15) << 2;
    int jg = j0 + j;
    float4 v = make_float4(0, 0, 0, 0);
    if (jg == 0)
      v = *(const float4*)(nullk + h * DH + d4);
    else if (jg < N_SEQ + 1)
      v = *(const float4*)(kv + ((size_t)(b * N_SEQ) + jg - 1) * 2048 + h * DH + d4);
    Ks[d4 + 0][j] = v.x; Ks[d4 + 1][j] = v.y; Ks[d4 + 2][j] = v.z; Ks[d4 + 3][j] = v.w;
  }
  __syncthreads();
  float acc[4][4];
#pragma unroll
  for (int i = 0; i < 4; i++)
#pragma unroll
    for (int j = 0; j < 4; j++) acc[i][j] = 0.f;
#pragma unroll 16
  for (int d = 0; d < 64; d++) {
    float av[4], bv[4];
    *(float4*)av = *(const float4*)&Qs[d][ty * 4];
    *(float4*)bv = *(const float4*)&Ks[d][tx * 4];
#pragma unroll
    for (int i = 0; i < 4; i++)
#pragma unroll
      for (int j = 0; j < 4; j++) acc[i][j] = fmaf(av[i], bv[j], acc[i][j]);
  }
#pragma unroll
  for (int ii = 0; ii < 4; ii++) {
    int i = i0 + ty * 4 + ii;
#pragma unroll
    for (int jj = 0; jj < 4; jj++) {
      int j = j0 + tx * 4 + jj;
      if (j < N_SEQ + 1) {
        float s = acc[ii][jj] * 0.125f;  // SCALE = 64^-0.5
        if (j > i + 1) s = -FLT_MAX;     // causal (null slot j=0 never masked)
        probs[((size_t)h * N_SEQ + i) * PSTRIDE + j] = s;
      }
    }
  }
}

// ---------------- row softmax over 1025 entries ----------------
__global__ __launch_bounds__(256) void softmax_kernel(float* __restrict__ probs) {
  __shared__ float red[4];
  const int row = blockIdx.x;  // h*1024 + i
  float* p = probs + (size_t)row * PSTRIDE;
  const int t = threadIdx.x;
  float v[5];
#pragma unroll
  for (int c = 0; c < 5; c++) {
    int j = t + c * 256;
    v[c] = (j < N_SEQ + 1) ? p[j] : -FLT_MAX;
  }
  float m = fmaxf(fmaxf(fmaxf(v[0], v[1]), fmaxf(v[2], v[3])), v[4]);
  m = block_max(m, red);
  float s = 0.f;
#pragma unroll
  for (int c = 0; c < 5; c++) {
    v[c] = expf(v[c] - m);
    s += v[c];
  }
  s = block_sum(s, red);
#pragma unroll
  for (int c = 0; c < 5; c++) {
    int j = t + c * 256;
    if (j < N_SEQ + 1) p[j] = v[c] / s;
  }
}

// ---------------- talking-heads mix (in place) ----------------
__global__ __launch_bounds__(256) void mix_kernel(float* __restrict__ probs,
                                                  const float* __restrict__ talk) {
  __shared__ float tk[256];
  const int i = blockIdx.x;
  tk[threadIdx.x] = talk[threadIdx.x];
  __syncthreads();
  for (int j = threadIdx.x; j < N_SEQ + 1; j += 256) {
    float a[16];
#pragma unroll
    for (int hh = 0; hh < 16; hh++) a[hh] = probs[((size_t)hh * N_SEQ + i) * PSTRIDE + j];
#pragma unroll
    for (int g = 0; g < 16; g++) {
      float s = 0.f;
#pragma unroll
      for (int hh = 0; hh < 16; hh++) s = fmaf(tk[g * 16 + hh], a[hh], s);
      probs[((size_t)g * N_SEQ + i) * PSTRIDE + j] = s;
    }
  }
}

// ---------------- AV: o[b,i,h*64+d] = sum_j p[h,i,j] * v[h,j,d] ----------------
__global__ __launch_bounds__(256) void av_kernel(const float* __restrict__ probs,
                                                 const float* __restrict__ kv,
                                                 const float* __restrict__ nullv,
                                                 float* __restrict__ o, int b) {
  __shared__ float Ps[32][68];  // [j][i]
  __shared__ float Vs[32][68];  // [j][d]
  const int h = blockIdx.y, i0 = blockIdx.x * 64;
  const int t = threadIdx.x, tx = t & 15, ty = t >> 4;
  float acc[4][4];
#pragma unroll
  for (int i = 0; i < 4; i++)
#pragma unroll
    for (int j = 0; j < 4; j++) acc[i][j] = 0.f;

  for (int j0 = 0; j0 < N_SEQ + 1; j0 += 32) {
#pragma unroll
    for (int r = 0; r < 2; r++) {
      int f = t + r * 256;
      int i = f >> 3, j4 = (f & 7) << 2;
      const float* src = probs + ((size_t)h * N_SEQ + i0 + i) * PSTRIDE + j0 + j4;
      float e[4];
      if (j0 + j4 + 3 < N_SEQ + 1) {
        float4 v = *(const float4*)src;
        e[0] = v.x; e[1] = v.y; e[2] = v.z; e[3] = v.w;
      } else {
#pragma unroll
        for (int c = 0; c < 4; c++) e[c] = (j0 + j4 + c < N_SEQ + 1) ? src[c] : 0.f;
      }
      Ps[j4 + 0][i] = e[0]; Ps[j4 + 1][i] = e[1]; Ps[j4 + 2][i] = e[2]; Ps[j4 + 3][i] = e[3];
    }
#pragma unroll
    for (int r = 0; r < 2; r++) {
      int f = t + r * 256;
      int j = f >> 4, d4 = (f & 15) << 2;
      int jg = j0 + j;
      float4 v = make_float4(0, 0, 0, 0);
      if (jg == 0)
        v = *(const float4*)(nullv + h * DH + d4);
      else if (jg < N_SEQ + 1)
        v = *(const float4*)(kv + ((size_t)(b * N_SEQ) + jg - 1) * 2048 + 1024 + h * DH + d4);
      *(float4*)&Vs[j][d4] = v;
    }
    __syncthreads();
#pragma unroll 8
    for (int jj = 0; jj < 32; jj++) {
      float av[4], bv[4];
      *(float4*)av = *(const float4*)&Ps[jj][ty * 4];
      *(float4*)bv = *(const float4*)&Vs[jj][tx * 4];
#pragma unroll
      for (int i = 0; i < 4; i++)
#pragma unroll
        for (int j = 0; j < 4; j++) acc[i][j] = fmaf(av[i], bv[j], acc[i][j]);
    }
    __syncthreads();
  }
#pragma unroll
  for (int ii = 0; ii < 4; ii++) {
    float4 v = make_float4(acc[ii][0], acc[ii][1], acc[ii][2], acc[ii][3]);
    *(float4*)(o + ((size_t)(b * N_SEQ) + i0 + ty * 4 + ii) * DMODEL + h * DH + tx * 4) = v;
  }
}

// ---------------- GEGLU: gg[i,c] = u[i,c] * gelu_exact(u[i,INNER+c]) ----------------
__global__ __launch_bounds__(256) void geglu_kernel(const float* __restrict__ u,
                                                    float* __restrict__ gg) {
  const int i = blockIdx.y;
  const int j = blockIdx.x * 256 + threadIdx.x;
  if (j < FF_INNER) {
    float a = u[(size_t)i * (2 * FF_INNER) + j];
    float x = u[(size_t)i * (2 * FF_INNER) + FF_INNER + j];
    float ge = 0.5f * x * (1.0f + erff(x * 0.70710678118654752f));
    gg[(size_t)i * GG_LD + j] = a * ge;
  }
}

// ---------------- launcher ----------------
extern "C" void kernel_launch(void* const* d_in, const int* in_sizes, int n_in,
                              void* d_out, int out_size, void* d_ws, size_t ws_size,
                              hipStream_t stream) {
  const float* xin        = (const float*)d_in[0];
  const float* attn_pre_g = (const float*)d_in[1];
  const float* attn_pre_b = (const float*)d_in[2];
  const float* attn_post_g= (const float*)d_in[3];
  const float* attn_post_b= (const float*)d_in[4];
  const float* Wq         = (const float*)d_in[5];
  const float* Wkv        = (const float*)d_in[6];
  const float* Wo         = (const float*)d_in[7];
  const float* bo         = (const float*)d_in[8];
  const float* null_k     = (const float*)d_in[9];
  const float* null_v     = (const float*)d_in[10];
  const float* talk       = (const float*)d_in[11];
  const float* ff_pre_g   = (const float*)d_in[12];
  const float* ff_pre_b   = (const float*)d_in[13];
  const float* ff_post_g  = (const float*)d_in[14];
  const float* ff_post_b  = (const float*)d_in[15];
  const float* W1         = (const float*)d_in[16];
  const float* b1         = (const float*)d_in[17];
  const float* W2         = (const float*)d_in[18];
  const float* b2         = (const float*)d_in[19];
  const float* final_g    = (const float*)d_in[20];
  const float* final_b    = (const float*)d_in[21];

  // ws requirement unchanged: 31,522,816 floats. Bail cleanly if short.
  const size_t WS_FLOATS_NEEDED = (size_t)31522816;
  if (ws_size < WS_FLOATS_NEEDED * sizeof(float)) return;

  float* ws = (float*)d_ws;
  float* X  = ws;                          // [2048][1024]
  float* Hh = X  + (size_t)2048 * 1024;    // [2048][1024]
  float* Q  = Hh + (size_t)2048 * 1024;    // [2048][1024]
  float* KV = Q  + (size_t)2048 * 1024;    // [2048][2048]
  float* O  = KV + (size_t)2048 * 2048;    // [2048][1024]
  float* P2 = O  + (size_t)2048 * 1024;    // [2048][1024]
  float* PR = P2 + (size_t)2048 * 1024;    // probs [16][1024][1028] / FF U,GG
  float* U  = PR;                          // [2048][5460]
  float* GG = PR + (size_t)2048 * 5460;    // [2048][2732] (padded rows)

  hipMemcpyAsync(X, xin, (size_t)2048 * 1024 * sizeof(float),
                 hipMemcpyDeviceToDevice, stream);

  dim3 blk(256);
  for (int l = 0; l < NLAYER; l++) {
    ln_kernel<0><<<2048, blk, 0, stream>>>(X, attn_pre_g + l * 1024, attn_pre_b + l * 1024, Hh);
    gemm_mfma<<<dim3(8, 16), blk, 0, stream>>>(Hh, Wq + (size_t)l * 1024 * 1024, nullptr, Q,
                                               1024, 1024, 1024);
    gemm_mfma<<<dim3(16, 16), blk, 0, stream>>>(Hh, Wkv + (size_t)l * 1024 * 2048, nullptr, KV,
                                                2048, 1024, 1024);
    for (int b = 0; b < 2; b++) {
      scores_kernel<<<dim3(17, 16, 16), blk, 0, stream>>>(Q, KV, null_k + l * NH * DH, PR, b);
      softmax_kernel<<<16384, blk, 0, stream>>>(PR);
      mix_kernel<<<1024, blk, 0, stream>>>(PR, talk + l * 256);
      av_kernel<<<dim3(16, 16), blk, 0, stream>>>(PR, KV, null_v + l * NH * DH, O, b);
    }
    gemm_mfma<<<dim3(8, 16), blk, 0, stream>>>(O, Wo + (size_t)l * 1024 * 1024, bo + l * 1024, P2,
                                               1024, 1024, 1024);
    ln_kernel<1><<<2048, blk, 0, stream>>>(P2, attn_post_g + l * 1024, attn_post_b + l * 1024, X);

    ln_kernel<0><<<2048, blk, 0, stream>>>(X, ff_pre_g + l * 1024, ff_pre_b + l * 1024, Hh);
    gemm_mfma<<<dim3(43, 16), blk, 0, stream>>>(Hh, W1 + (size_t)l * 1024 * 5460, b1 + l * 5460, U,
                                                5460, 1024, 1024);
    geglu_kernel<<<dim3(11, 2048), blk, 0, stream>>>(U, GG);
    gemm_mfma<<<dim3(8, 16), blk, 0, stream>>>(GG, W2 + (size_t)l * 2730 * 1024, b2 + l * 1024, P2,
                                               1024, 2730, GG_LD);
    ln_kernel<1><<<2048, blk, 0, stream>>>(P2, ff_post_g + l * 1024, ff_post_b + l * 1024, X);
  }
  final_kernel<<<2048, blk, 0, stream>>>(X, final_g, final_b, (float*)d_out);
}

// Round 5
// 3977.602 us; speedup vs baseline: 3.2931x; 3.2931x over previous
//
#include <hip/hip_runtime.h>
#include <hip/hip_bf16.h>
#include <float.h>
#include <math.h>

// Transformer forward. Round 4 (resubmit): m97-style bf16 GEMM.
//  - producers write bf16 (LN, av, geglu); weights pre-converted+transposed
//    per layer (cvtT) into Wt[N][K] bf16, zero-padded.
//  - gemm_bf16: global_load_lds(16B) staging, single LDS buffer,
//    ds_read_b128 fragments, mfma_f32_16x16x32_bf16, fp32 epilogue + bias.
// B=2, N=1024, D=1024, H=16, DH=64, L=6, INNER=2730.
// ws (floats): X(2M) | Hbf(1M) | Q(2M) | KV(4M) | Obf(1M) | P2(2M) | PR(16.84M)
//   PR reuse: attn probs [16][1024][1028]  OR  U[2048][5460] fp32 +
//             GGbf[2048][2752] bf16 + Wt[<=5504][<=2752] bf16 (11.27 MB).
// Total: 29,425,664 floats = 117,702,656 bytes.

#define N_SEQ 1024
#define DMODEL 1024
#define NH 16
#define DH 64
#define NLAYER 6
#define FF_INNER 2730
#define K2PAD 2752     // FF_INNER padded to mult of 32
#define PSTRIDE 1028   // padded row stride for probs rows of length 1025

typedef float f32x4 __attribute__((ext_vector_type(4)));
typedef short s16x8 __attribute__((ext_vector_type(8)));
typedef unsigned long long u64;

__device__ __forceinline__ ushort f2bf(float f) {
  return __builtin_bit_cast(ushort, __float2bfloat16(f));
}
__device__ __forceinline__ u64 pack4(float a, float b, float c, float d) {
  return (u64)f2bf(a) | ((u64)f2bf(b) << 16) | ((u64)f2bf(c) << 32) |
         ((u64)f2bf(d) << 48);
}
#define GLD_LDS16(g, l)                                                        \
  __builtin_amdgcn_global_load_lds(                                            \
      (const __attribute__((address_space(1))) void*)(g),                      \
      (__attribute__((address_space(3))) void*)(l), 16, 0, 0)

// ---------------- block reductions (256 threads = 4 waves) ----------------
__device__ __forceinline__ float wave_sum(float v) {
#pragma unroll
  for (int o = 32; o > 0; o >>= 1) v += __shfl_xor(v, o, 64);
  return v;
}
__device__ __forceinline__ float wave_max(float v) {
#pragma unroll
  for (int o = 32; o > 0; o >>= 1) v = fmaxf(v, __shfl_xor(v, o, 64));
  return v;
}
__device__ __forceinline__ float block_sum(float v, float* s) {
  v = wave_sum(v);
  __syncthreads();
  if ((threadIdx.x & 63) == 0) s[threadIdx.x >> 6] = v;
  __syncthreads();
  return s[0] + s[1] + s[2] + s[3];
}
__device__ __forceinline__ float block_max(float v, float* s) {
  v = wave_max(v);
  __syncthreads();
  if ((threadIdx.x & 63) == 0) s[threadIdx.x >> 6] = v;
  __syncthreads();
  return fmaxf(fmaxf(s[0], s[1]), fmaxf(s[2], s[3]));
}

// ---------------- LayerNorm -> fp32 out (residual add) ----------------
__global__ __launch_bounds__(256) void ln_res_kernel(const float* __restrict__ in,
                                                     const float* __restrict__ gw,
                                                     const float* __restrict__ bw,
                                                     float* __restrict__ out) {
  __shared__ float red[4];
  const int row = blockIdx.x, t = threadIdx.x;
  float4 v = *(const float4*)(in + (size_t)row * DMODEL + t * 4);
  float mean = block_sum(v.x + v.y + v.z + v.w, red) * (1.0f / DMODEL);
  float4 d = make_float4(v.x - mean, v.y - mean, v.z - mean, v.w - mean);
  float var = block_sum(d.x * d.x + d.y * d.y + d.z * d.z + d.w * d.w, red) * (1.0f / DMODEL);
  float rstd = rsqrtf(var + 1e-5f);
  float4 g4 = *(const float4*)(gw + t * 4);
  float4 b4 = *(const float4*)(bw + t * 4);
  float* q = out + (size_t)row * DMODEL + t * 4;
  float4 xv = *(float4*)q;
  xv.x += d.x * rstd * g4.x + b4.x;
  xv.y += d.y * rstd * g4.y + b4.y;
  xv.z += d.z * rstd * g4.z + b4.z;
  xv.w += d.w * rstd * g4.w + b4.w;
  *(float4*)q = xv;
}

// ---------------- LayerNorm -> bf16 out ----------------
__global__ __launch_bounds__(256) void ln_bf16_kernel(const float* __restrict__ in,
                                                      const float* __restrict__ gw,
                                                      const float* __restrict__ bw,
                                                      ushort* __restrict__ out) {
  __shared__ float red[4];
  const int row = blockIdx.x, t = threadIdx.x;
  float4 v = *(const float4*)(in + (size_t)row * DMODEL + t * 4);
  float mean = block_sum(v.x + v.y + v.z + v.w, red) * (1.0f / DMODEL);
  float4 d = make_float4(v.x - mean, v.y - mean, v.z - mean, v.w - mean);
  float var = block_sum(d.x * d.x + d.y * d.y + d.z * d.z + d.w * d.w, red) * (1.0f / DMODEL);
  float rstd = rsqrtf(var + 1e-5f);
  float4 g4 = *(const float4*)(gw + t * 4);
  float4 b4 = *(const float4*)(bw + t * 4);
  *(u64*)(out + (size_t)row * DMODEL + t * 4) =
      pack4(d.x * rstd * g4.x + b4.x, d.y * rstd * g4.y + b4.y,
            d.z * rstd * g4.z + b4.z, d.w * rstd * g4.w + b4.w);
}

// ---------------- final: x / rowmax(x), then LN ----------------
__global__ __launch_bounds__(256) void final_kernel(const float* __restrict__ in,
                                                    const float* __restrict__ gw,
                                                    const float* __restrict__ bw,
                                                    float* __restrict__ out) {
  __shared__ float red[4];
  const int row = blockIdx.x, t = threadIdx.x;
  float4 v = *(const float4*)(in + (size_t)row * DMODEL + t * 4);
  float mx = block_max(fmaxf(fmaxf(v.x, v.y), fmaxf(v.z, v.w)), red);
  float4 y = make_float4(v.x / mx, v.y / mx, v.z / mx, v.w / mx);
  float mean = block_sum(y.x + y.y + y.z + y.w, red) * (1.0f / DMODEL);
  float4 d = make_float4(y.x - mean, y.y - mean, y.z - mean, y.w - mean);
  float var = block_sum(d.x * d.x + d.y * d.y + d.z * d.z + d.w * d.w, red) * (1.0f / DMODEL);
  float rstd = rsqrtf(var + 1e-5f);
  float4 g4 = *(const float4*)(gw + t * 4);
  float4 b4 = *(const float4*)(bw + t * 4);
  float4 r = make_float4(d.x * rstd * g4.x + b4.x, d.y * rstd * g4.y + b4.y,
                         d.z * rstd * g4.z + b4.z, d.w * rstd * g4.w + b4.w);
  *(float4*)(out + (size_t)row * DMODEL + t * 4) = r;
}

// ---------------- weight convert+transpose: W[K][N] fp32 -> Wt[Npad][Kpad] bf16 ----------------
// grid (Npad/32, Kpad/32); zero-fills n>=N, k>=K.
__global__ __launch_bounds__(256) void cvtT_kernel(const float* __restrict__ W,
                                                   ushort* __restrict__ Wt,
                                                   int K, int N, int Kpad) {
  __shared__ float tile[32][33];
  const int n0 = blockIdx.x * 32, k0 = blockIdx.y * 32;
  const int tr = threadIdx.x >> 3, tc4 = (threadIdx.x & 7) * 4;
  int gk = k0 + tr;
  float4 v = make_float4(0, 0, 0, 0);
  if (gk < K) {
    if (n0 + tc4 + 3 < N) {
      v = *(const float4*)(W + (size_t)gk * N + n0 + tc4);
    } else {
      if (n0 + tc4 + 0 < N) v.x = W[(size_t)gk * N + n0 + tc4 + 0];
      if (n0 + tc4 + 1 < N) v.y = W[(size_t)gk * N + n0 + tc4 + 1];
      if (n0 + tc4 + 2 < N) v.z = W[(size_t)gk * N + n0 + tc4 + 2];
      if (n0 + tc4 + 3 < N) v.w = W[(size_t)gk * N + n0 + tc4 + 3];
    }
  }
  tile[tr][tc4 + 0] = v.x; tile[tr][tc4 + 1] = v.y;
  tile[tr][tc4 + 2] = v.z; tile[tr][tc4 + 3] = v.w;
  __syncthreads();
  // Wt[n0+tr][k0+tc4+c] = tile[tc4+c][tr]
  *(u64*)(Wt + (size_t)(n0 + tr) * Kpad + k0 + tc4) =
      pack4(tile[tc4 + 0][tr], tile[tc4 + 1][tr], tile[tc4 + 2][tr], tile[tc4 + 3][tr]);
}

// ---------------- bf16 GEMM (m97 structure) ----------------
// C[M,N] = A[M,K] @ Bt[N,K]^T (+bias). A,Bt bf16 row-major (row strides lda,ldb,
// multiples of 8). M=2048, grid (Npad/128, M/128). K mult of 32 (zero-padded).
// 256 thr = 4 waves (2x2), wave = 64x64 out = 4x4 frags of 16x16x32.
__global__ __launch_bounds__(256) void gemm_bf16(const ushort* __restrict__ A,
                                                 const ushort* __restrict__ Bt,
                                                 const float* __restrict__ bias,
                                                 float* __restrict__ C,
                                                 int N, int K, int lda, int ldb) {
  __shared__ __align__(16) ushort Al[128 * 32];
  __shared__ __align__(16) ushort Bl[128 * 32];
  const int n0 = blockIdx.x * 128, m0 = blockIdx.y * 128;
  const int t = threadIdx.x, lane = t & 63, w = t >> 6;
  const int wm = w >> 1, wn = w & 1;

  f32x4 acc[4][4];
#pragma unroll
  for (int i = 0; i < 4; i++)
#pragma unroll
    for (int j = 0; j < 4; j++) acc[i][j] = (f32x4){0.f, 0.f, 0.f, 0.f};

  // staging: thread t covers tile row t>>2 (and +64), k-offset (t&3)*8
  const int sm = t >> 2, sk = (t & 3) * 8;
  const ushort* ga0 = A + (size_t)(m0 + sm) * lda + sk;
  const ushort* ga1 = ga0 + (size_t)64 * lda;
  const ushort* gb0 = Bt + (size_t)(n0 + sm) * ldb + sk;
  const ushort* gb1 = gb0 + (size_t)64 * ldb;
  ushort* la0 = &Al[t * 8];
  ushort* la1 = &Al[2048 + t * 8];
  ushort* lb0 = &Bl[t * 8];
  ushort* lb1 = &Bl[2048 + t * 8];

  const int kk = (lane >> 4) * 8;
  const int rA = wm * 64 + (lane & 15);
  const int rB = wn * 64 + (lane & 15);

  for (int k0 = 0; k0 < K; k0 += 32) {
    GLD_LDS16(ga0 + k0, la0);
    GLD_LDS16(ga1 + k0, la1);
    GLD_LDS16(gb0 + k0, lb0);
    GLD_LDS16(gb1 + k0, lb1);
    __syncthreads();
    s16x8 fa[4], fb[4];
#pragma unroll
    for (int mi = 0; mi < 4; mi++)
      fa[mi] = *(const s16x8*)&Al[(rA + mi * 16) * 32 + kk];
#pragma unroll
    for (int ni = 0; ni < 4; ni++)
      fb[ni] = *(const s16x8*)&Bl[(rB + ni * 16) * 32 + kk];
#pragma unroll
    for (int mi = 0; mi < 4; mi++)
#pragma unroll
      for (int ni = 0; ni < 4; ni++)
        acc[mi][ni] = __builtin_amdgcn_mfma_f32_16x16x32_bf16(
            fa[mi], fb[ni], acc[mi][ni], 0, 0, 0);
    __syncthreads();
  }

  const int crow = m0 + wm * 64 + (lane >> 4) * 4;
  const int ccol = n0 + wn * 64 + (lane & 15);
#pragma unroll
  for (int ni = 0; ni < 4; ni++) {
    int gc = ccol + ni * 16;
    if (gc >= N) continue;
    float bv = bias ? bias[gc] : 0.f;
#pragma unroll
    for (int mi = 0; mi < 4; mi++)
#pragma unroll
      for (int r = 0; r < 4; r++)
        C[(size_t)(crow + mi * 16 + r) * N + gc] = acc[mi][ni][r] + bv;
  }
}

// ---------------- attention scores (fp32; unchanged) ----------------
__global__ __launch_bounds__(256) void scores_kernel(const float* __restrict__ q,
                                                     const float* __restrict__ kv,
                                                     const float* __restrict__ nullk,
                                                     float* __restrict__ probs, int b) {
  __shared__ float Qs[64][68];
  __shared__ float Ks[64][68];
  const int h = blockIdx.z, i0 = blockIdx.y * 64, j0 = blockIdx.x * 64;
  const int t = threadIdx.x, tx = t & 15, ty = t >> 4;
#pragma unroll
  for (int r = 0; r < 4; r++) {
    int f = t + r * 256;
    int i = f >> 4, d4 = (f & 15) << 2;
    float4 v = *(const float4*)(q + ((size_t)(b * N_SEQ) + i0 + i) * DMODEL + h * DH + d4);
    Qs[d4 + 0][i] = v.x; Qs[d4 + 1][i] = v.y; Qs[d4 + 2][i] = v.z; Qs[d4 + 3][i] = v.w;
  }
#pragma unroll
  for (int r = 0; r < 4; r++) {
    int f = t + r * 256;
    int j = f >> 4, d4 = (f & 15) << 2;
    int jg = j0 + j;
    float4 v = make_float4(0, 0, 0, 0);
    if (jg == 0)
      v = *(const float4*)(nullk + h * DH + d4);
    else if (jg < N_SEQ + 1)
      v = *(const float4*)(kv + ((size_t)(b * N_SEQ) + jg - 1) * 2048 + h * DH + d4);
    Ks[d4 + 0][j] = v.x; Ks[d4 + 1][j] = v.y; Ks[d4 + 2][j] = v.z; Ks[d4 + 3][j] = v.w;
  }
  __syncthreads();
  float acc[4][4];
#pragma unroll
  for (int i = 0; i < 4; i++)
#pragma unroll
    for (int j = 0; j < 4; j++) acc[i][j] = 0.f;
#pragma unroll 16
  for (int d = 0; d < 64; d++) {
    float av[4], bv[4];
    *(float4*)av = *(const float4*)&Qs[d][ty * 4];
    *(float4*)bv = *(const float4*)&Ks[d][tx * 4];
#pragma unroll
    for (int i = 0; i < 4; i++)
#pragma unroll
      for (int j = 0; j < 4; j++) acc[i][j] = fmaf(av[i], bv[j], acc[i][j]);
  }
#pragma unroll
  for (int ii = 0; ii < 4; ii++) {
    int i = i0 + ty * 4 + ii;
#pragma unroll
    for (int jj = 0; jj < 4; jj++) {
      int j = j0 + tx * 4 + jj;
      if (j < N_SEQ + 1) {
        float s = acc[ii][jj] * 0.125f;
        if (j > i + 1) s = -FLT_MAX;
        probs[((size_t)h * N_SEQ + i) * PSTRIDE + j] = s;
      }
    }
  }
}

// ---------------- row softmax over 1025 entries ----------------
__global__ __launch_bounds__(256) void softmax_kernel(float* __restrict__ probs) {
  __shared__ float red[4];
  const int row = blockIdx.x;
  float* p = probs + (size_t)row * PSTRIDE;
  const int t = threadIdx.x;
  float v[5];
#pragma unroll
  for (int c = 0; c < 5; c++) {
    int j = t + c * 256;
    v[c] = (j < N_SEQ + 1) ? p[j] : -FLT_MAX;
  }
  float m = fmaxf(fmaxf(fmaxf(v[0], v[1]), fmaxf(v[2], v[3])), v[4]);
  m = block_max(m, red);
  float s = 0.f;
#pragma unroll
  for (int c = 0; c < 5; c++) {
    v[c] = expf(v[c] - m);
    s += v[c];
  }
  s = block_sum(s, red);
#pragma unroll
  for (int c = 0; c < 5; c++) {
    int j = t + c * 256;
    if (j < N_SEQ + 1) p[j] = v[c] / s;
  }
}

// ---------------- talking-heads mix (in place) ----------------
__global__ __launch_bounds__(256) void mix_kernel(float* __restrict__ probs,
                                                  const float* __restrict__ talk) {
  __shared__ float tk[256];
  const int i = blockIdx.x;
  tk[threadIdx.x] = talk[threadIdx.x];
  __syncthreads();
  for (int j = threadIdx.x; j < N_SEQ + 1; j += 256) {
    float a[16];
#pragma unroll
    for (int hh = 0; hh < 16; hh++) a[hh] = probs[((size_t)hh * N_SEQ + i) * PSTRIDE + j];
#pragma unroll
    for (int g = 0; g < 16; g++) {
      float s = 0.f;
#pragma unroll
      for (int hh = 0; hh < 16; hh++) s = fmaf(tk[g * 16 + hh], a[hh], s);
      probs[((size_t)g * N_SEQ + i) * PSTRIDE + j] = s;
    }
  }
}

// ---------------- AV: bf16 out ----------------
__global__ __launch_bounds__(256) void av_kernel(const float* __restrict__ probs,
                                                 const float* __restrict__ kv,
                                                 const float* __restrict__ nullv,
                                                 ushort* __restrict__ o, int b) {
  __shared__ float Ps[32][68];
  __shared__ float Vs[32][68];
  const int h = blockIdx.y, i0 = blockIdx.x * 64;
  const int t = threadIdx.x, tx = t & 15, ty = t >> 4;
  float acc[4][4];
#pragma unroll
  for (int i = 0; i < 4; i++)
#pragma unroll
    for (int j = 0; j < 4; j++) acc[i][j] = 0.f;

  for (int j0 = 0; j0 < N_SEQ + 1; j0 += 32) {
#pragma unroll
    for (int r = 0; r < 2; r++) {
      int f = t + r * 256;
      int i = f >> 3, j4 = (f & 7) << 2;
      const float* src = probs + ((size_t)h * N_SEQ + i0 + i) * PSTRIDE + j0 + j4;
      float e[4];
      if (j0 + j4 + 3 < N_SEQ + 1) {
        float4 v = *(const float4*)src;
        e[0] = v.x; e[1] = v.y; e[2] = v.z; e[3] = v.w;
      } else {
#pragma unroll
        for (int c = 0; c < 4; c++) e[c] = (j0 + j4 + c < N_SEQ + 1) ? src[c] : 0.f;
      }
      Ps[j4 + 0][i] = e[0]; Ps[j4 + 1][i] = e[1]; Ps[j4 + 2][i] = e[2]; Ps[j4 + 3][i] = e[3];
    }
#pragma unroll
    for (int r = 0; r < 2; r++) {
      int f = t + r * 256;
      int j = f >> 4, d4 = (f & 15) << 2;
      int jg = j0 + j;
      float4 v = make_float4(0, 0, 0, 0);
      if (jg == 0)
        v = *(const float4*)(nullv + h * DH + d4);
      else if (jg < N_SEQ + 1)
        v = *(const float4*)(kv + ((size_t)(b * N_SEQ) + jg - 1) * 2048 + 1024 + h * DH + d4);
      *(float4*)&Vs[j][d4] = v;
    }
    __syncthreads();
#pragma unroll 8
    for (int jj = 0; jj < 32; jj++) {
      float av[4], bv[4];
      *(float4*)av = *(const float4*)&Ps[jj][ty * 4];
      *(float4*)bv = *(const float4*)&Vs[jj][tx * 4];
#pragma unroll
      for (int i = 0; i < 4; i++)
#pragma unroll
        for (int j = 0; j < 4; j++) acc[i][j] = fmaf(av[i], bv[j], acc[i][j]);
    }
    __syncthreads();
  }
#pragma unroll
  for (int ii = 0; ii < 4; ii++) {
    *(u64*)(o + ((size_t)(b * N_SEQ) + i0 + ty * 4 + ii) * DMODEL + h * DH + tx * 4) =
        pack4(acc[ii][0], acc[ii][1], acc[ii][2], acc[ii][3]);
  }
}

// ---------------- GEGLU: bf16 out, K-padded with zeros ----------------
__global__ __launch_bounds__(256) void geglu_kernel(const float* __restrict__ u,
                                                    ushort* __restrict__ gg) {
  const int i = blockIdx.y;
  const int j = blockIdx.x * 256 + threadIdx.x;
  if (j < K2PAD) {
    float r = 0.f;
    if (j < FF_INNER) {
      float a = u[(size_t)i * (2 * FF_INNER) + j];
      float x = u[(size_t)i * (2 * FF_INNER) + FF_INNER + j];
      r = a * 0.5f * x * (1.0f + erff(x * 0.70710678118654752f));
    }
    gg[(size_t)i * K2PAD + j] = f2bf(r);
  }
}

// ---------------- launcher ----------------
extern "C" void kernel_launch(void* const* d_in, const int* in_sizes, int n_in,
                              void* d_out, int out_size, void* d_ws, size_t ws_size,
                              hipStream_t stream) {
  const float* xin        = (const float*)d_in[0];
  const float* attn_pre_g = (const float*)d_in[1];
  const float* attn_pre_b = (const float*)d_in[2];
  const float* attn_post_g= (const float*)d_in[3];
  const float* attn_post_b= (const float*)d_in[4];
  const float* Wq         = (const float*)d_in[5];
  const float* Wkv        = (const float*)d_in[6];
  const float* Wo         = (const float*)d_in[7];
  const float* bo         = (const float*)d_in[8];
  const float* null_k     = (const float*)d_in[9];
  const float* null_v     = (const float*)d_in[10];
  const float* talk       = (const float*)d_in[11];
  const float* ff_pre_g   = (const float*)d_in[12];
  const float* ff_pre_b   = (const float*)d_in[13];
  const float* ff_post_g  = (const float*)d_in[14];
  const float* ff_post_b  = (const float*)d_in[15];
  const float* W1         = (const float*)d_in[16];
  const float* b1         = (const float*)d_in[17];
  const float* W2         = (const float*)d_in[18];
  const float* b2         = (const float*)d_in[19];
  const float* final_g    = (const float*)d_in[20];
  const float* final_b    = (const float*)d_in[21];

  // ws requirement: 29,425,664 floats = 117,702,656 bytes.
  if (ws_size < (size_t)29425664 * sizeof(float)) return;

  float* ws = (float*)d_ws;
  float*  X   = ws;                               // [2048][1024] fp32
  ushort* Hbf = (ushort*)(X + (size_t)2097152);   // [2048][1024] bf16 (1M fe)
  float*  Q   = (float*)(Hbf) + 1048576;          // [2048][1024] fp32
  float*  KV  = Q + (size_t)2097152;              // [2048][2048] fp32
  ushort* Obf = (ushort*)(KV + (size_t)4194304);  // [2048][1024] bf16 (1M fe)
  float*  P2  = (float*)(Obf) + 1048576;          // [2048][1024] fp32
  float*  PR  = P2 + (size_t)2097152;             // 16,842,752 floats
  // PR overlays:
  float*  PROBS = PR;                             // [16][1024][1028] fp32
  float*  U     = PR;                             // [2048][5460] fp32 (11,182,080)
  ushort* GGbf  = (ushort*)(PR + 11182080);       // [2048][2752] bf16 (2,818,048 fe)
  ushort* Wt    = (ushort*)(PR + 14000128);       // up to 5504*1024 bf16 (2,818,048 fe)

  hipMemcpyAsync(X, xin, (size_t)2097152 * sizeof(float),
                 hipMemcpyDeviceToDevice, stream);

  dim3 blk(256);
  for (int l = 0; l < NLAYER; l++) {
    // ---- attention ----
    ln_bf16_kernel<<<2048, blk, 0, stream>>>(X, attn_pre_g + l * 1024, attn_pre_b + l * 1024, Hbf);
    cvtT_kernel<<<dim3(32, 32), blk, 0, stream>>>(Wq + (size_t)l * 1048576, Wt, 1024, 1024, 1024);
    gemm_bf16<<<dim3(8, 16), blk, 0, stream>>>(Hbf, Wt, nullptr, Q, 1024, 1024, 1024, 1024);
    cvtT_kernel<<<dim3(64, 32), blk, 0, stream>>>(Wkv + (size_t)l * 2097152, Wt, 1024, 2048, 1024);
    gemm_bf16<<<dim3(16, 16), blk, 0, stream>>>(Hbf, Wt, nullptr, KV, 2048, 1024, 1024, 1024);
    for (int b = 0; b < 2; b++) {
      scores_kernel<<<dim3(17, 16, 16), blk, 0, stream>>>(Q, KV, null_k + l * NH * DH, PROBS, b);
      softmax_kernel<<<16384, blk, 0, stream>>>(PROBS);
      mix_kernel<<<1024, blk, 0, stream>>>(PROBS, talk + l * 256);
      av_kernel<<<dim3(16, 16), blk, 0, stream>>>(PROBS, KV, null_v + l * NH * DH, Obf, b);
    }
    cvtT_kernel<<<dim3(32, 32), blk, 0, stream>>>(Wo + (size_t)l * 1048576, Wt, 1024, 1024, 1024);
    gemm_bf16<<<dim3(8, 16), blk, 0, stream>>>(Obf, Wt, bo + l * 1024, P2, 1024, 1024, 1024, 1024);
    ln_res_kernel<<<2048, blk, 0, stream>>>(P2, attn_post_g + l * 1024, attn_post_b + l * 1024, X);

    // ---- feedforward ----
    ln_bf16_kernel<<<2048, blk, 0, stream>>>(X, ff_pre_g + l * 1024, ff_pre_b + l * 1024, Hbf);
    cvtT_kernel<<<dim3(172, 32), blk, 0, stream>>>(W1 + (size_t)l * 5591040, Wt, 1024, 5460, 1024);
    gemm_bf16<<<dim3(43, 16), blk, 0, stream>>>(Hbf, Wt, b1 + l * 5460, U, 5460, 1024, 1024, 1024);
    geglu_kernel<<<dim3(11, 2048), blk, 0, stream>>>(U, GGbf);
    cvtT_kernel<<<dim3(32, 86), blk, 0, stream>>>(W2 + (size_t)l * 2795520, Wt, 2730, 1024, K2PAD);
    gemm_bf16<<<dim3(8, 16), blk, 0, stream>>>(GGbf, Wt, b2 + l * 1024, P2, 1024, K2PAD, K2PAD, K2PAD);
    ln_res_kernel<<<2048, blk, 0, stream>>>(P2, ff_post_g + l * 1024, ff_post_b + l * 1024, X);
  }
  final_kernel<<<2048, blk, 0, stream>>>(X, final_g, final_b, (float*)d_out);
}

// Round 8
// 3233.006 us; speedup vs baseline: 4.0515x; 1.2303x over previous
//
#include <hip/hip_runtime.h>
#include <hip/hip_bf16.h>
#include <float.h>
#include <math.h>

// Transformer forward. Round 6 (2nd resubmit): MFMA attention + fused softmax/talk-mix.
// B=2, N=1024, D=1024, H=16, DH=64, L=6, INNER=2730.
// ws layout (floats), total 28,217,344 f = 112,869,376 B:
//  X 2,097,152 | Hbf/Obf 1,048,576 | Qbf 1,048,576 |
//  union{KVbf 2,097,152 | PB[16][1024][1056]bf16 8,437,760} |
//  P2 2,097,152 | Kh[2][16][1152][64]bf16 1,179,648 | Vt[2][16][64][1056]bf16 1,081,344 |
//  BIG 11,227,136 = union{PROBS[16][512][1028]f32 8,421,376 |
//                          Ubf 5,591,040 + GGbf 2,818,048 + Wt 2,818,048}

#define N_SEQ 1024
#define DMODEL 1024
#define NLAYER 6
#define FF_INNER 2730
#define K2PAD 2752     // FF_INNER padded to mult of 32
#define PSTR 1028      // fp32 scores row stride
#define PBSTR 1056     // bf16 probs / Vt row stride (mult of 32)
#define KHROWS 1152    // Kh padded rows (9 n-tiles of 128)

typedef float f32x4 __attribute__((ext_vector_type(4)));
typedef short s16x8 __attribute__((ext_vector_type(8)));
typedef unsigned long long u64;

__device__ __forceinline__ ushort f2bf(float f) {
  return __builtin_bit_cast(ushort, __float2bfloat16(f));
}
__device__ __forceinline__ float bf2f(ushort u) {
  union { unsigned i; float f; } x; x.i = ((unsigned)u) << 16; return x.f;
}
__device__ __forceinline__ u64 pack4(float a, float b, float c, float d) {
  return (u64)f2bf(a) | ((u64)f2bf(b) << 16) | ((u64)f2bf(c) << 32) |
         ((u64)f2bf(d) << 48);
}
#define GLD_LDS16(g, l)                                                        \
  __builtin_amdgcn_global_load_lds(                                            \
      (const __attribute__((address_space(1))) void*)(g),                      \
      (__attribute__((address_space(3))) void*)(l), 16, 0, 0)

// ---------------- block reductions (256 threads = 4 waves) ----------------
__device__ __forceinline__ float wave_sum(float v) {
#pragma unroll
  for (int o = 32; o > 0; o >>= 1) v += __shfl_xor(v, o, 64);
  return v;
}
__device__ __forceinline__ float wave_max(float v) {
#pragma unroll
  for (int o = 32; o > 0; o >>= 1) v = fmaxf(v, __shfl_xor(v, o, 64));
  return v;
}
__device__ __forceinline__ float block_sum(float v, float* s) {
  v = wave_sum(v);
  __syncthreads();
  if ((threadIdx.x & 63) == 0) s[threadIdx.x >> 6] = v;
  __syncthreads();
  return s[0] + s[1] + s[2] + s[3];
}
__device__ __forceinline__ float block_max(float v, float* s) {
  v = wave_max(v);
  __syncthreads();
  if ((threadIdx.x & 63) == 0) s[threadIdx.x >> 6] = v;
  __syncthreads();
  return fmaxf(fmaxf(s[0], s[1]), fmaxf(s[2], s[3]));
}

// ---------------- LayerNorm -> fp32 residual add ----------------
__global__ __launch_bounds__(256) void ln_res_kernel(const float* __restrict__ in,
                                                     const float* __restrict__ gw,
                                                     const float* __restrict__ bw,
                                                     float* __restrict__ out) {
  __shared__ float red[4];
  const int row = blockIdx.x, t = threadIdx.x;
  float4 v = *(const float4*)(in + (size_t)row * DMODEL + t * 4);
  float mean = block_sum(v.x + v.y + v.z + v.w, red) * (1.0f / DMODEL);
  float4 d = make_float4(v.x - mean, v.y - mean, v.z - mean, v.w - mean);
  float var = block_sum(d.x * d.x + d.y * d.y + d.z * d.z + d.w * d.w, red) * (1.0f / DMODEL);
  float rstd = rsqrtf(var + 1e-5f);
  float4 g4 = *(const float4*)(gw + t * 4);
  float4 b4 = *(const float4*)(bw + t * 4);
  float* q = out + (size_t)row * DMODEL + t * 4;
  float4 xv = *(float4*)q;
  xv.x += d.x * rstd * g4.x + b4.x;
  xv.y += d.y * rstd * g4.y + b4.y;
  xv.z += d.z * rstd * g4.z + b4.z;
  xv.w += d.w * rstd * g4.w + b4.w;
  *(float4*)q = xv;
}

// ---------------- LayerNorm -> bf16 out ----------------
__global__ __launch_bounds__(256) void ln_bf16_kernel(const float* __restrict__ in,
                                                      const float* __restrict__ gw,
                                                      const float* __restrict__ bw,
                                                      ushort* __restrict__ out) {
  __shared__ float red[4];
  const int row = blockIdx.x, t = threadIdx.x;
  float4 v = *(const float4*)(in + (size_t)row * DMODEL + t * 4);
  float mean = block_sum(v.x + v.y + v.z + v.w, red) * (1.0f / DMODEL);
  float4 d = make_float4(v.x - mean, v.y - mean, v.z - mean, v.w - mean);
  float var = block_sum(d.x * d.x + d.y * d.y + d.z * d.z + d.w * d.w, red) * (1.0f / DMODEL);
  float rstd = rsqrtf(var + 1e-5f);
  float4 g4 = *(const float4*)(gw + t * 4);
  float4 b4 = *(const float4*)(bw + t * 4);
  *(u64*)(out + (size_t)row * DMODEL + t * 4) =
      pack4(d.x * rstd * g4.x + b4.x, d.y * rstd * g4.y + b4.y,
            d.z * rstd * g4.z + b4.z, d.w * rstd * g4.w + b4.w);
}

// ---------------- final: x / rowmax(x), then LN ----------------
__global__ __launch_bounds__(256) void final_kernel(const float* __restrict__ in,
                                                    const float* __restrict__ gw,
                                                    const float* __restrict__ bw,
                                                    float* __restrict__ out) {
  __shared__ float red[4];
  const int row = blockIdx.x, t = threadIdx.x;
  float4 v = *(const float4*)(in + (size_t)row * DMODEL + t * 4);
  float mx = block_max(fmaxf(fmaxf(v.x, v.y), fmaxf(v.z, v.w)), red);
  float4 y = make_float4(v.x / mx, v.y / mx, v.z / mx, v.w / mx);
  float mean = block_sum(y.x + y.y + y.z + y.w, red) * (1.0f / DMODEL);
  float4 d = make_float4(y.x - mean, y.y - mean, y.z - mean, y.w - mean);
  float var = block_sum(d.x * d.x + d.y * d.y + d.z * d.z + d.w * d.w, red) * (1.0f / DMODEL);
  float rstd = rsqrtf(var + 1e-5f);
  float4 g4 = *(const float4*)(gw + t * 4);
  float4 b4 = *(const float4*)(bw + t * 4);
  float4 r = make_float4(d.x * rstd * g4.x + b4.x, d.y * rstd * g4.y + b4.y,
                         d.z * rstd * g4.z + b4.z, d.w * rstd * g4.w + b4.w);
  *(float4*)(out + (size_t)row * DMODEL + t * 4) = r;
}

// ---------------- weight convert+transpose: W[K][N] fp32 -> Wt[Npad][Kpad] bf16 ----------------
__global__ __launch_bounds__(256) void cvtT_kernel(const float* __restrict__ W,
                                                   ushort* __restrict__ Wt,
                                                   int K, int N, int Kpad) {
  __shared__ float tile[32][33];
  const int n0 = blockIdx.x * 32, k0 = blockIdx.y * 32;
  const int tr = threadIdx.x >> 3, tc4 = (threadIdx.x & 7) * 4;
  int gk = k0 + tr;
  float4 v = make_float4(0, 0, 0, 0);
  if (gk < K) {
    if (n0 + tc4 + 3 < N) {
      v = *(const float4*)(W + (size_t)gk * N + n0 + tc4);
    } else {
      if (n0 + tc4 + 0 < N) v.x = W[(size_t)gk * N + n0 + tc4 + 0];
      if (n0 + tc4 + 1 < N) v.y = W[(size_t)gk * N + n0 + tc4 + 1];
      if (n0 + tc4 + 2 < N) v.z = W[(size_t)gk * N + n0 + tc4 + 2];
      if (n0 + tc4 + 3 < N) v.w = W[(size_t)gk * N + n0 + tc4 + 3];
    }
  }
  tile[tr][tc4 + 0] = v.x; tile[tr][tc4 + 1] = v.y;
  tile[tr][tc4 + 2] = v.z; tile[tr][tc4 + 3] = v.w;
  __syncthreads();
  *(u64*)(Wt + (size_t)(n0 + tr) * Kpad + k0 + tc4) =
      pack4(tile[tc4 + 0][tr], tile[tc4 + 1][tr], tile[tc4 + 2][tr], tile[tc4 + 3][tr]);
}

// ---------------- bf16 GEMM (m97 structure), templated output dtype ----------------
// C[2048,N] = A[2048,K] @ Bt[N,K]^T (+bias). OBF: 1 -> bf16 out, 0 -> fp32 out.
template <int OBF>
__global__ __launch_bounds__(256) void gemm_bf16(const ushort* __restrict__ A,
                                                 const ushort* __restrict__ Bt,
                                                 const float* __restrict__ bias,
                                                 void* __restrict__ Cv,
                                                 int N, int K, int lda, int ldb) {
  __shared__ __align__(16) ushort Al[128 * 32];
  __shared__ __align__(16) ushort Bl[128 * 32];
  const int n0 = blockIdx.x * 128, m0 = blockIdx.y * 128;
  const int t = threadIdx.x, lane = t & 63, w = t >> 6;
  const int wm = w >> 1, wn = w & 1;

  f32x4 acc[4][4];
#pragma unroll
  for (int i = 0; i < 4; i++)
#pragma unroll
    for (int j = 0; j < 4; j++) acc[i][j] = (f32x4){0.f, 0.f, 0.f, 0.f};

  const int sm = t >> 2, sk = (t & 3) * 8;
  const ushort* ga0 = A + (size_t)(m0 + sm) * lda + sk;
  const ushort* ga1 = ga0 + (size_t)64 * lda;
  const ushort* gb0 = Bt + (size_t)(n0 + sm) * ldb + sk;
  const ushort* gb1 = gb0 + (size_t)64 * ldb;
  ushort* la0 = &Al[t * 8];
  ushort* la1 = &Al[2048 + t * 8];
  ushort* lb0 = &Bl[t * 8];
  ushort* lb1 = &Bl[2048 + t * 8];

  const int kk = (lane >> 4) * 8;
  const int rA = wm * 64 + (lane & 15);
  const int rB = wn * 64 + (lane & 15);

  for (int k0 = 0; k0 < K; k0 += 32) {
    GLD_LDS16(ga0 + k0, la0);
    GLD_LDS16(ga1 + k0, la1);
    GLD_LDS16(gb0 + k0, lb0);
    GLD_LDS16(gb1 + k0, lb1);
    __syncthreads();
    s16x8 fa[4], fb[4];
#pragma unroll
    for (int mi = 0; mi < 4; mi++)
      fa[mi] = *(const s16x8*)&Al[(rA + mi * 16) * 32 + kk];
#pragma unroll
    for (int ni = 0; ni < 4; ni++)
      fb[ni] = *(const s16x8*)&Bl[(rB + ni * 16) * 32 + kk];
#pragma unroll
    for (int mi = 0; mi < 4; mi++)
#pragma unroll
      for (int ni = 0; ni < 4; ni++)
        acc[mi][ni] = __builtin_amdgcn_mfma_f32_16x16x32_bf16(
            fa[mi], fb[ni], acc[mi][ni], 0, 0, 0);
    __syncthreads();
  }

  const int crow = m0 + wm * 64 + (lane >> 4) * 4;
  const int ccol = n0 + wn * 64 + (lane & 15);
#pragma unroll
  for (int ni = 0; ni < 4; ni++) {
    int gc = ccol + ni * 16;
    if (gc >= N) continue;
    float bv = bias ? bias[gc] : 0.f;
#pragma unroll
    for (int mi = 0; mi < 4; mi++)
#pragma unroll
      for (int r = 0; r < 4; r++) {
        float val = acc[mi][ni][r] + bv;
        size_t off = (size_t)(crow + mi * 16 + r) * N + gc;
        if (OBF) ((ushort*)Cv)[off] = f2bf(val);
        else     ((float*)Cv)[off]  = val;
      }
  }
}

// ---------------- prep: KVbf -> Kh [b,h][1152][64], Vt [b,h][64][1056] ----------------
__global__ __launch_bounds__(256) void prep_kv(const ushort* __restrict__ KVbf,
                                               const float* __restrict__ nk,
                                               const float* __restrict__ nv,
                                               ushort* __restrict__ Kh,
                                               ushort* __restrict__ Vt) {
  const int b = blockIdx.x >> 4, h = blockIdx.x & 15;
  const int t = threadIdx.x;
  ushort* khb = Kh + (size_t)(b * 16 + h) * KHROWS * 64;
  for (int idx = t; idx < KHROWS * 16; idx += 256) {  // u64 chunks (64/4 per row)
    int j = idx >> 4, c4 = (idx & 15) * 4;
    u64 v = 0;
    if (j == 0) {
      v = pack4(nk[h * 64 + c4], nk[h * 64 + c4 + 1],
                nk[h * 64 + c4 + 2], nk[h * 64 + c4 + 3]);
    } else if (j <= N_SEQ) {
      v = *(const u64*)&KVbf[(size_t)(b * N_SEQ + j - 1) * 2048 + h * 64 + c4];
    }
    *(u64*)&khb[j * 64 + c4] = v;
  }
  ushort* vtb = Vt + (size_t)(b * 16 + h) * 64 * PBSTR;
  for (int idx = t; idx < PBSTR * 16; idx += 256) {   // per j: 16 chunks of 4 d
    int j = idx >> 4, d4 = (idx & 15) * 4;
    ushort e0 = 0, e1 = 0, e2 = 0, e3 = 0;
    if (j == 0) {
      e0 = f2bf(nv[h * 64 + d4]);     e1 = f2bf(nv[h * 64 + d4 + 1]);
      e2 = f2bf(nv[h * 64 + d4 + 2]); e3 = f2bf(nv[h * 64 + d4 + 3]);
    } else if (j <= N_SEQ) {
      u64 v = *(const u64*)&KVbf[(size_t)(b * N_SEQ + j - 1) * 2048 + 1024 + h * 64 + d4];
      e0 = (ushort)v; e1 = (ushort)(v >> 16); e2 = (ushort)(v >> 32); e3 = (ushort)(v >> 48);
    }
    vtb[(d4 + 0) * PBSTR + j] = e0;
    vtb[(d4 + 1) * PBSTR + j] = e1;
    vtb[(d4 + 2) * PBSTR + j] = e2;
    vtb[(d4 + 3) * PBSTR + j] = e3;
  }
}

// ---------------- scores: PROBS[h][i-half][j] = 0.125 * q_i . k_j (MFMA) ----------------
// grid (tj=9, til=4, h=16) per (b, ihalf). Fully-masked tiles skipped entirely
// (smmix only reads j <= i+1).
__global__ __launch_bounds__(256) void scores_mfma(const ushort* __restrict__ Qbf,
                                                   const ushort* __restrict__ Kh,
                                                   float* __restrict__ probs,
                                                   int b, int ihalf) {
  const int tj = blockIdx.x, til = blockIdx.y, h = blockIdx.z;
  const int ti = ihalf * 4 + til;
  const int m0 = ti * 128, n0 = tj * 128;
  if (n0 > m0 + 128) return;  // tile entirely masked; never read downstream
  __shared__ __align__(16) ushort Al[128 * 32];
  __shared__ __align__(16) ushort Bl[128 * 32];
  const int t = threadIdx.x, lane = t & 63, w = t >> 6;
  const int wm = w >> 1, wn = w & 1;

  f32x4 acc[4][4];
#pragma unroll
  for (int i = 0; i < 4; i++)
#pragma unroll
    for (int j = 0; j < 4; j++) acc[i][j] = (f32x4){0.f, 0.f, 0.f, 0.f};

  const int sm = t >> 2, sk = (t & 3) * 8;
  const ushort* ga0 = Qbf + (size_t)(b * N_SEQ + m0 + sm) * DMODEL + h * 64 + sk;
  const ushort* ga1 = ga0 + (size_t)64 * DMODEL;
  const ushort* gb0 = Kh + ((size_t)(b * 16 + h) * KHROWS + n0 + sm) * 64 + sk;
  const ushort* gb1 = gb0 + (size_t)64 * 64;
  ushort* la0 = &Al[t * 8];
  ushort* la1 = &Al[2048 + t * 8];
  ushort* lb0 = &Bl[t * 8];
  ushort* lb1 = &Bl[2048 + t * 8];

  const int kk = (lane >> 4) * 8;
  const int rA = wm * 64 + (lane & 15);
  const int rB = wn * 64 + (lane & 15);

#pragma unroll
  for (int k0 = 0; k0 < 64; k0 += 32) {
    GLD_LDS16(ga0 + k0, la0);
    GLD_LDS16(ga1 + k0, la1);
    GLD_LDS16(gb0 + k0, lb0);
    GLD_LDS16(gb1 + k0, lb1);
    __syncthreads();
    s16x8 fa[4], fb[4];
#pragma unroll
    for (int mi = 0; mi < 4; mi++)
      fa[mi] = *(const s16x8*)&Al[(rA + mi * 16) * 32 + kk];
#pragma unroll
    for (int ni = 0; ni < 4; ni++)
      fb[ni] = *(const s16x8*)&Bl[(rB + ni * 16) * 32 + kk];
#pragma unroll
    for (int mi = 0; mi < 4; mi++)
#pragma unroll
      for (int ni = 0; ni < 4; ni++)
        acc[mi][ni] = __builtin_amdgcn_mfma_f32_16x16x32_bf16(
            fa[mi], fb[ni], acc[mi][ni], 0, 0, 0);
    __syncthreads();
  }

  const int crow = m0 + wm * 64 + (lane >> 4) * 4;   // global i
  const int ccol = n0 + wn * 64 + (lane & 15);       // j
#pragma unroll
  for (int ni = 0; ni < 4; ni++) {
    int gc = ccol + ni * 16;
    if (gc >= PSTR) continue;
#pragma unroll
    for (int mi = 0; mi < 4; mi++)
#pragma unroll
      for (int r = 0; r < 4; r++) {
        int ig = crow + mi * 16 + r;
        probs[((size_t)h * 512 + (ig & 511)) * PSTR + gc] = acc[mi][ni][r] * 0.125f;
      }
  }
}

// ---------------- fused softmax + talking-heads mix -> bf16 probs ----------------
// one block per row i (512 per dispatch); all 16 heads staged in LDS.
__global__ __launch_bounds__(256) void smmix_kernel(const float* __restrict__ probs,
                                                    const float* __restrict__ talk,
                                                    ushort* __restrict__ PB, int ihalf) {
  __shared__ __align__(16) float sl[16][PSTR];
  __shared__ float tk[16][16];
  __shared__ float ms[16], rls[16];
  const int il = blockIdx.x;
  const int ig = ihalf * 512 + il;
  const int jmax = ig + 2;                  // valid j in [0, jmax)
  const int t = threadIdx.x;
  tk[t >> 4][t & 15] = talk[t];
  const int nch = (jmax + 3) >> 2;
  for (int idx = t; idx < 16 * nch; idx += 256) {
    int h = idx / nch, c = idx - h * nch;
    *(float4*)&sl[h][c * 4] = *(const float4*)&probs[((size_t)h * 512 + il) * PSTR + c * 4];
  }
  __syncthreads();
  {
    const int h = t >> 4, l16 = t & 15;
    float m = -FLT_MAX;
    for (int j = l16; j < jmax; j += 16) m = fmaxf(m, sl[h][j]);
#pragma unroll
    for (int o = 1; o < 16; o <<= 1) m = fmaxf(m, __shfl_xor(m, o, 16));
    float s = 0.f;
    for (int j = l16; j < jmax; j += 16) s += expf(sl[h][j] - m);
#pragma unroll
    for (int o = 1; o < 16; o <<= 1) s += __shfl_xor(s, o, 16);
    if (l16 == 0) { ms[h] = m; rls[h] = 1.0f / s; }
  }
  __syncthreads();
  for (int idx = t; idx < 16 * 257; idx += 256) {  // p = exp(s-m)/l, zero pad
    int h = idx / 257, c = idx - h * 257;
    float4 v = *(float4*)&sl[h][c * 4];
    float m = ms[h], rl = rls[h];
    int j = c * 4;
    v.x = (j + 0 < jmax) ? expf(v.x - m) * rl : 0.f;
    v.y = (j + 1 < jmax) ? expf(v.y - m) * rl : 0.f;
    v.z = (j + 2 < jmax) ? expf(v.z - m) * rl : 0.f;
    v.w = (j + 3 < jmax) ? expf(v.w - m) * rl : 0.f;
    *(float4*)&sl[h][c * 4] = v;
  }
  __syncthreads();
  for (int idx = t; idx < 16 * (PBSTR / 4); idx += 256) {  // mix + bf16 write
    int g = idx / (PBSTR / 4), c = idx - g * (PBSTR / 4);
    float ax = 0.f, ay = 0.f, az = 0.f, aw = 0.f;
    if (c < 257) {
#pragma unroll
      for (int h = 0; h < 16; h++) {
        float4 p = *(float4*)&sl[h][c * 4];
        float wgh = tk[g][h];
        ax += wgh * p.x; ay += wgh * p.y; az += wgh * p.z; aw += wgh * p.w;
      }
    }
    *(u64*)&PB[((size_t)g * N_SEQ + ig) * PBSTR + c * 4] = pack4(ax, ay, az, aw);
  }
}

// ---------------- AV: o[b,i,g*64+d] = sum_j pb[g,i,j] * v[g,j,d] (MFMA) ----------------
// grid (ti=16 (64-row tiles), g=16) per b. 64x64 tile, K=1056.
__global__ __launch_bounds__(256) void av_mfma(const ushort* __restrict__ PB,
                                               const ushort* __restrict__ Vt,
                                               ushort* __restrict__ Obf, int b) {
  __shared__ __align__(16) ushort Al[64 * 32];
  __shared__ __align__(16) ushort Bl[64 * 32];
  const int m0 = blockIdx.x * 64, g = blockIdx.y;
  const int t = threadIdx.x, lane = t & 63, w = t >> 6;
  const int wm = w >> 1, wn = w & 1;
  f32x4 acc[2][2];
#pragma unroll
  for (int i = 0; i < 2; i++)
#pragma unroll
    for (int j = 0; j < 2; j++) acc[i][j] = (f32x4){0.f, 0.f, 0.f, 0.f};

  const int sm = t >> 2, sk = (t & 3) * 8;
  const ushort* ga = PB + ((size_t)g * N_SEQ + m0 + sm) * PBSTR + sk;
  const ushort* gb = Vt + ((size_t)(b * 16 + g) * 64 + sm) * PBSTR + sk;
  ushort* la = &Al[t * 8];
  ushort* lb = &Bl[t * 8];

  const int kk = (lane >> 4) * 8;
  const int rA = wm * 32 + (lane & 15);
  const int rB = wn * 32 + (lane & 15);

  for (int k0 = 0; k0 < PBSTR; k0 += 32) {
    GLD_LDS16(ga + k0, la);
    GLD_LDS16(gb + k0, lb);
    __syncthreads();
    s16x8 fa[2], fb[2];
    fa[0] = *(const s16x8*)&Al[rA * 32 + kk];
    fa[1] = *(const s16x8*)&Al[(rA + 16) * 32 + kk];
    fb[0] = *(const s16x8*)&Bl[rB * 32 + kk];
    fb[1] = *(const s16x8*)&Bl[(rB + 16) * 32 + kk];
#pragma unroll
    for (int mi = 0; mi < 2; mi++)
#pragma unroll
      for (int ni = 0; ni < 2; ni++)
        acc[mi][ni] = __builtin_amdgcn_mfma_f32_16x16x32_bf16(
            fa[mi], fb[ni], acc[mi][ni], 0, 0, 0);
    __syncthreads();
  }

  const int crow = m0 + wm * 32 + (lane >> 4) * 4;
  const int ccol = wn * 32 + (lane & 15);
#pragma unroll
  for (int ni = 0; ni < 2; ni++)
#pragma unroll
    for (int mi = 0; mi < 2; mi++)
#pragma unroll
      for (int r = 0; r < 4; r++)
        Obf[(size_t)(b * N_SEQ + crow + mi * 16 + r) * DMODEL + g * 64 + ccol + ni * 16] =
            f2bf(acc[mi][ni][r]);
}

// ---------------- GEGLU: bf16 in/out ----------------
__global__ __launch_bounds__(256) void geglu_kernel(const ushort* __restrict__ u,
                                                    ushort* __restrict__ gg) {
  const int i = blockIdx.y;
  const int j = blockIdx.x * 256 + threadIdx.x;
  if (j < K2PAD) {
    float r = 0.f;
    if (j < FF_INNER) {
      float a = bf2f(u[(size_t)i * (2 * FF_INNER) + j]);
      float x = bf2f(u[(size_t)i * (2 * FF_INNER) + FF_INNER + j]);
      r = a * 0.5f * x * (1.0f + erff(x * 0.70710678118654752f));
    }
    gg[(size_t)i * K2PAD + j] = f2bf(r);
  }
}

// ---------------- launcher ----------------
extern "C" void kernel_launch(void* const* d_in, const int* in_sizes, int n_in,
                              void* d_out, int out_size, void* d_ws, size_t ws_size,
                              hipStream_t stream) {
  const float* xin        = (const float*)d_in[0];
  const float* attn_pre_g = (const float*)d_in[1];
  const float* attn_pre_b = (const float*)d_in[2];
  const float* attn_post_g= (const float*)d_in[3];
  const float* attn_post_b= (const float*)d_in[4];
  const float* Wq         = (const float*)d_in[5];
  const float* Wkv        = (const float*)d_in[6];
  const float* Wo         = (const float*)d_in[7];
  const float* bo         = (const float*)d_in[8];
  const float* null_k     = (const float*)d_in[9];
  const float* null_v     = (const float*)d_in[10];
  const float* talk       = (const float*)d_in[11];
  const float* ff_pre_g   = (const float*)d_in[12];
  const float* ff_pre_b   = (const float*)d_in[13];
  const float* ff_post_g  = (const float*)d_in[14];
  const float* ff_post_b  = (const float*)d_in[15];
  const float* W1         = (const float*)d_in[16];
  const float* b1         = (const float*)d_in[17];
  const float* W2         = (const float*)d_in[18];
  const float* b2         = (const float*)d_in[19];
  const float* final_g    = (const float*)d_in[20];
  const float* final_b    = (const float*)d_in[21];

  // total ws requirement: 28,217,344 floats = 112,869,376 bytes
  if (ws_size < (size_t)28217344 * sizeof(float)) return;

  float* ws = (float*)d_ws;
  float*  X    = ws;                               // 2,097,152 f
  ushort* Hbf  = (ushort*)(ws + 2097152);          // 2,097,152 u (bf16 2048x1024)
  ushort* Obf  = Hbf;                              // overlay (disjoint lifetime)
  ushort* Qbf  = (ushort*)(ws + 3145728);          // 2,097,152 u
  ushort* KVbf = (ushort*)(ws + 4194304);          // 4,194,304 u
  ushort* PB   = (ushort*)(ws + 4194304);          // overlay: 16,875,520 u
  float*  P2   = ws + 12632064;                    // 2,097,152 f
  ushort* Kh   = (ushort*)(ws + 14729216);         // 2,359,296 u
  ushort* Vt   = (ushort*)(ws + 15908864);         // 2,162,688 u
  float*  BIG  = ws + 16990208;                    // 11,227,136 f
  float*  PROBS = BIG;                             // [16][512][1028] f32
  ushort* Ubf   = (ushort*)BIG;                    // [2048][5460] bf16
  ushort* GGbf  = (ushort*)(BIG + 5591040);        // [2048][2752] bf16
  ushort* Wt    = (ushort*)(BIG + 8409088);        // up to [5504][1024] bf16

  hipMemcpyAsync(X, xin, (size_t)2097152 * sizeof(float),
                 hipMemcpyDeviceToDevice, stream);

  dim3 blk(256);
  for (int l = 0; l < NLAYER; l++) {
    // ---- attention ----
    ln_bf16_kernel<<<2048, blk, 0, stream>>>(X, attn_pre_g + l * 1024, attn_pre_b + l * 1024, Hbf);
    cvtT_kernel<<<dim3(32, 32), blk, 0, stream>>>(Wq + (size_t)l * 1048576, Wt, 1024, 1024, 1024);
    gemm_bf16<1><<<dim3(8, 16), blk, 0, stream>>>(Hbf, Wt, nullptr, Qbf, 1024, 1024, 1024, 1024);
    cvtT_kernel<<<dim3(64, 32), blk, 0, stream>>>(Wkv + (size_t)l * 2097152, Wt, 1024, 2048, 1024);
    gemm_bf16<1><<<dim3(16, 16), blk, 0, stream>>>(Hbf, Wt, nullptr, KVbf, 2048, 1024, 1024, 1024);
    prep_kv<<<32, blk, 0, stream>>>(KVbf, null_k + l * 1024, null_v + l * 1024, Kh, Vt);
    for (int b = 0; b < 2; b++) {
      for (int ih = 0; ih < 2; ih++) {
        scores_mfma<<<dim3(9, 4, 16), blk, 0, stream>>>(Qbf, Kh, PROBS, b, ih);
        smmix_kernel<<<512, blk, 0, stream>>>(PROBS, talk + l * 256, PB, ih);
      }
      av_mfma<<<dim3(16, 16), blk, 0, stream>>>(PB, Vt, Obf, b);
    }
    cvtT_kernel<<<dim3(32, 32), blk, 0, stream>>>(Wo + (size_t)l * 1048576, Wt, 1024, 1024, 1024);
    gemm_bf16<0><<<dim3(8, 16), blk, 0, stream>>>(Obf, Wt, bo + l * 1024, P2, 1024, 1024, 1024, 1024);
    ln_res_kernel<<<2048, blk, 0, stream>>>(P2, attn_post_g + l * 1024, attn_post_b + l * 1024, X);

    // ---- feedforward ----
    ln_bf16_kernel<<<2048, blk, 0, stream>>>(X, ff_pre_g + l * 1024, ff_pre_b + l * 1024, Hbf);
    cvtT_kernel<<<dim3(172, 32), blk, 0, stream>>>(W1 + (size_t)l * 5591040, Wt, 1024, 5460, 1024);
    gemm_bf16<1><<<dim3(43, 16), blk, 0, stream>>>(Hbf, Wt, b1 + l * 5460, Ubf, 5460, 1024, 1024, 1024);
    geglu_kernel<<<dim3(11, 2048), blk, 0, stream>>>(Ubf, GGbf);
    cvtT_kernel<<<dim3(32, 86), blk, 0, stream>>>(W2 + (size_t)l * 2795520, Wt, 2730, 1024, K2PAD);
    gemm_bf16<0><<<dim3(8, 16), blk, 0, stream>>>(GGbf, Wt, b2 + l * 1024, P2, 1024, K2PAD, K2PAD, K2PAD);
    ln_res_kernel<<<2048, blk, 0, stream>>>(P2, ff_post_g + l * 1024, ff_post_b + l * 1024, X);
  }
  final_kernel<<<2048, blk, 0, stream>>>(X, final_g, final_b, (float*)d_out);
}